// Round 3
// baseline (1178.107 us; speedup 1.0000x reference)
//
#include <hip/hip_runtime.h>

// Segment-mean ("centers") kernel for MI355X.
// inputs:  [N, D] f32,  targets: [N] i32,  classes: scalar (unused; derived),
// class_weight: [C, D] f32  ->  out: [C, D] f32
// ws layout: sums f32[C*D] | counts f32[C]

typedef float floatx4 __attribute__((ext_vector_type(4)));

__global__ void zero_ws_kernel(float4* __restrict__ ws4, unsigned total4) {
    unsigned idx = blockIdx.x * blockDim.x + threadIdx.x;
    unsigned stride = gridDim.x * blockDim.x;
    float4 z = {0.f, 0.f, 0.f, 0.f};
    for (; idx < total4; idx += stride) ws4[idx] = z;
}

__global__ void accum_kernel(const floatx4* __restrict__ in4,
                             const int* __restrict__ targets,
                             float* __restrict__ sums,
                             float* __restrict__ counts,
                             unsigned total4, int shift, unsigned mask, int d) {
    unsigned idx = blockIdx.x * blockDim.x + threadIdx.x;
    unsigned stride = gridDim.x * blockDim.x;
    for (; idx < total4; idx += stride) {
        unsigned row = idx >> shift;     // input row
        unsigned c4  = idx & mask;       // float4 index within the row
        int t = targets[row];            // wave-uniform (64 consecutive c4 share a row)
        floatx4 v = __builtin_nontemporal_load(&in4[idx]);  // streamed once
        float* dst = sums + (size_t)t * d + (c4 << 2);
        atomicAdd(dst + 0, v.x);
        atomicAdd(dst + 1, v.y);
        atomicAdd(dst + 2, v.z);
        atomicAdd(dst + 3, v.w);
        if (c4 == 0) atomicAdd(counts + t, 1.0f);
    }
}

__global__ void finalize_kernel(const float4* __restrict__ sums4,
                                const float4* __restrict__ w4,
                                const float* __restrict__ counts,
                                float4* __restrict__ out4,
                                unsigned totalc4, int shift) {
    unsigned idx = blockIdx.x * blockDim.x + threadIdx.x;
    if (idx >= totalc4) return;
    unsigned c = idx >> shift;           // class id
    float cnt = counts[c];
    float4 r;
    if (cnt > 0.0f) {
        float4 s = sums4[idx];
        float inv = 1.0f / cnt;
        r.x = s.x * inv; r.y = s.y * inv; r.z = s.z * inv; r.w = s.w * inv;
    } else {
        r = w4[idx];
    }
    out4[idx] = r;
}

extern "C" void kernel_launch(void* const* d_in, const int* in_sizes, int n_in,
                              void* d_out, int out_size, void* d_ws, size_t ws_size,
                              hipStream_t stream) {
    const float* inputs = (const float*)d_in[0];
    const int* targets  = (const int*)d_in[1];
    // d_in[2] is the scalar `classes`; shapes derived from in_sizes instead.
    const float* weight = (const float*)d_in[3];

    const int N = in_sizes[1];                 // 65536
    const int D = in_sizes[0] / N;             // 1024
    const int C = in_sizes[3] / D;             // 1000
    const int D4 = D / 4;                      // 256 (power of two)

    int shift = 0;
    while ((1 << shift) < D4) ++shift;         // log2(D4) = 8
    unsigned mask = (unsigned)(D4 - 1);

    float* sums   = (float*)d_ws;
    float* counts = sums + (size_t)C * D;

    // Zero accumulators (ws is re-poisoned to 0xAA before every call).
    unsigned zero4 = ((unsigned)C * (unsigned)D + (unsigned)C + 3u) / 4u;
    zero_ws_kernel<<<1024, 256, 0, stream>>>((float4*)d_ws, zero4);

    // Pass 1: scatter-accumulate.
    unsigned total4 = (unsigned)N * (unsigned)D4;   // 16,777,216
    accum_kernel<<<2048, 256, 0, stream>>>(
        (const floatx4*)inputs, targets, sums, counts, total4, shift, mask, D);

    // Pass 2: finalize (mean or fallback weight).
    unsigned totalc4 = (unsigned)C * (unsigned)D4;  // 256,000
    int fblocks = (int)((totalc4 + 255) / 256);
    finalize_kernel<<<fblocks, 256, 0, stream>>>(
        (const float4*)sums, (const float4*)weight, counts,
        (float4*)d_out, totalc4, shift);
}

// Round 4
// 412.593 us; speedup vs baseline: 2.8554x; 2.8554x over previous
//
#include <hip/hip_runtime.h>

// Segment-mean ("centers") via bin-then-gather (no atomics on the heavy pass).
// inputs: [N, D] f32, targets: [N] i32, classes: scalar (derived), class_weight: [C, D] f32
// out: [C, D] f32
// ws layout: counts i32[C] | cursors i32[C] | offsets i32[C] | binned i32[N]

typedef float floatx4 __attribute__((ext_vector_type(4)));

__global__ void zero_kernel(int* __restrict__ p, int n) {
    int i = blockIdx.x * blockDim.x + threadIdx.x;
    if (i < n) p[i] = 0;
}

__global__ void count_kernel(const int* __restrict__ targets, int* __restrict__ counts, int n) {
    int i = blockIdx.x * blockDim.x + threadIdx.x;
    if (i < n) atomicAdd(&counts[targets[i]], 1);
}

// Single-block exclusive scan (Hillis-Steele, double-buffered). C <= 1024.
__global__ void scan_kernel(const int* __restrict__ counts, int* __restrict__ offsets, int c) {
    __shared__ int buf[2][1024];
    int tid = threadIdx.x;
    int v = (tid < c) ? counts[tid] : 0;
    buf[0][tid] = v;
    __syncthreads();
    int src = 0;
    for (int d = 1; d < 1024; d <<= 1) {
        int x = buf[src][tid];
        if (tid >= d) x += buf[src][tid - d];
        buf[src ^ 1][tid] = x;
        src ^= 1;
        __syncthreads();
    }
    if (tid < c) offsets[tid] = buf[src][tid] - v;   // exclusive
}

__global__ void scatter_kernel(const int* __restrict__ targets,
                               const int* __restrict__ offsets,
                               int* __restrict__ cursors,
                               int* __restrict__ binned, int n) {
    int i = blockIdx.x * blockDim.x + threadIdx.x;
    if (i < n) {
        int t = targets[i];
        int pos = atomicAdd(&cursors[t], 1);
        binned[offsets[t] + pos] = i;
    }
}

// One block per class; 256 threads x float4 = one full 4KB row per iteration.
__global__ void gather_kernel(const floatx4* __restrict__ in4,
                              const floatx4* __restrict__ w4,
                              const int* __restrict__ counts,
                              const int* __restrict__ offsets,
                              const int* __restrict__ binned,
                              floatx4* __restrict__ out4, int d4) {
    int c = blockIdx.x;
    int tid = threadIdx.x;                     // 0..d4-1 (d4 == blockDim.x == 256)
    int cnt = counts[c];
    size_t obase = (size_t)c * d4 + tid;
    if (cnt == 0) {
        out4[obase] = w4[obase];
        return;
    }
    __shared__ int rows[2048];
    int off = offsets[c];
    floatx4 a0 = {0,0,0,0}, a1 = {0,0,0,0}, a2 = {0,0,0,0}, a3 = {0,0,0,0};
    for (int base = 0; base < cnt; base += 2048) {
        int m = min(cnt - base, 2048);
        __syncthreads();                        // protect rows[] reuse across chunks
        for (int j = tid; j < m; j += blockDim.x) rows[j] = binned[off + base + j];
        __syncthreads();
        int j = 0;
        for (; j + 3 < m; j += 4) {             // 4 independent load chains (ILP)
            int r0 = rows[j], r1 = rows[j+1], r2 = rows[j+2], r3 = rows[j+3];
            a0 += in4[(size_t)r0 * d4 + tid];
            a1 += in4[(size_t)r1 * d4 + tid];
            a2 += in4[(size_t)r2 * d4 + tid];
            a3 += in4[(size_t)r3 * d4 + tid];
        }
        for (; j < m; ++j) a0 += in4[(size_t)rows[j] * d4 + tid];
    }
    floatx4 s = (a0 + a1) + (a2 + a3);
    float inv = 1.0f / (float)cnt;
    out4[obase] = s * inv;
}

extern "C" void kernel_launch(void* const* d_in, const int* in_sizes, int n_in,
                              void* d_out, int out_size, void* d_ws, size_t ws_size,
                              hipStream_t stream) {
    const float* inputs = (const float*)d_in[0];
    const int* targets  = (const int*)d_in[1];
    const float* weight = (const float*)d_in[3];

    const int N = in_sizes[1];                 // 65536
    const int D = in_sizes[0] / N;             // 1024
    const int C = in_sizes[3] / D;             // 1000
    const int D4 = D / 4;                      // 256

    int* counts  = (int*)d_ws;
    int* cursors = counts + C;
    int* offsets = cursors + C;
    int* binned  = offsets + C;

    // 1. zero counts + cursors (ws is re-poisoned to 0xAA before every call)
    zero_kernel<<<(2 * C + 255) / 256, 256, 0, stream>>>(counts, 2 * C);

    // 2. histogram of targets
    count_kernel<<<(N + 255) / 256, 256, 0, stream>>>(targets, counts, N);

    // 3. exclusive prefix sum -> bin offsets
    scan_kernel<<<1, 1024, 0, stream>>>(counts, offsets, C);

    // 4. scatter row ids into bins
    scatter_kernel<<<(N + 255) / 256, 256, 0, stream>>>(targets, offsets, cursors, binned, N);

    // 5. per-class gather-reduce + finalize
    gather_kernel<<<C, D4, 0, stream>>>(
        (const floatx4*)inputs, (const floatx4*)weight,
        counts, offsets, binned, (floatx4*)d_out, D4);
}

// Round 6
// 391.486 us; speedup vs baseline: 3.0093x; 1.0539x over previous
//
#include <hip/hip_runtime.h>

// Segment-mean ("centers") via bin-then-gather (no atomics on the heavy pass).
// inputs: [N, D] f32, targets: [N] i32, classes: scalar (derived), class_weight: [C, D] f32
// out: [C, D] f32
// ws: counts i32[C] | cursors i32[C] | offsets i32[C] | binned i32[N] | part f32[2*C*D]

typedef float floatx4 __attribute__((ext_vector_type(4)));

__global__ void zero_kernel(int* __restrict__ p, int n) {
    int i = blockIdx.x * blockDim.x + threadIdx.x;
    if (i < n) p[i] = 0;
}

__global__ void count_kernel(const int* __restrict__ targets, int* __restrict__ counts, int n) {
    int i = blockIdx.x * blockDim.x + threadIdx.x;
    if (i < n) atomicAdd(&counts[targets[i]], 1);
}

// Single-block exclusive scan (Hillis-Steele). C <= 1024.
__global__ void scan_kernel(const int* __restrict__ counts, int* __restrict__ offsets, int c) {
    __shared__ int buf[2][1024];
    int tid = threadIdx.x;
    int v = (tid < c) ? counts[tid] : 0;
    buf[0][tid] = v;
    __syncthreads();
    int src = 0;
    for (int d = 1; d < 1024; d <<= 1) {
        int x = buf[src][tid];
        if (tid >= d) x += buf[src][tid - d];
        buf[src ^ 1][tid] = x;
        src ^= 1;
        __syncthreads();
    }
    if (tid < c) offsets[tid] = buf[src][tid] - v;   // exclusive
}

__global__ void scatter_kernel(const int* __restrict__ targets,
                               const int* __restrict__ offsets,
                               int* __restrict__ cursors,
                               int* __restrict__ binned, int n) {
    int i = blockIdx.x * blockDim.x + threadIdx.x;
    if (i < n) {
        int t = targets[i];
        int pos = atomicAdd(&cursors[t], 1);
        binned[offsets[t] + pos] = i;
    }
}

// Two blocks per class (row-halves); 256 threads x float4 = full row width.
// 2000 blocks x 4 waves = 8000 waves -> ~full occupancy.
__global__ void gather_kernel(const floatx4* __restrict__ in4,
                              const int* __restrict__ counts,
                              const int* __restrict__ offsets,
                              const int* __restrict__ binned,
                              floatx4* __restrict__ part4, int d4) {
    int b = blockIdx.x;
    int c = b >> 1, half = b & 1;
    int cnt = counts[c];
    if (cnt == 0) return;                      // finalize uses class_weight
    int mid = (cnt + 1) >> 1;
    int begin = half ? mid : 0;
    int end   = half ? cnt : mid;
    int off = offsets[c] + begin;
    int m = end - begin;                       // may be 0 (cnt==1, half==1): writes zeros
    int tid = threadIdx.x;                     // 0..255 == d4

    __shared__ int rows[1024];
    floatx4 a0 = {0,0,0,0}, a1 = {0,0,0,0}, a2 = {0,0,0,0}, a3 = {0,0,0,0};
    floatx4 a4 = {0,0,0,0}, a5 = {0,0,0,0}, a6 = {0,0,0,0}, a7 = {0,0,0,0};

    for (int base = 0; base < m; base += 1024) {
        int mm = min(m - base, 1024);
        __syncthreads();
        for (int j = tid; j < mm; j += blockDim.x) rows[j] = binned[off + base + j];
        __syncthreads();
        int j = 0;
        for (; j + 7 < mm; j += 8) {           // 8 independent load chains
            int r0 = rows[j],   r1 = rows[j+1], r2 = rows[j+2], r3 = rows[j+3];
            int r4 = rows[j+4], r5 = rows[j+5], r6 = rows[j+6], r7 = rows[j+7];
            a0 += __builtin_nontemporal_load(&in4[(size_t)r0 * d4 + tid]);
            a1 += __builtin_nontemporal_load(&in4[(size_t)r1 * d4 + tid]);
            a2 += __builtin_nontemporal_load(&in4[(size_t)r2 * d4 + tid]);
            a3 += __builtin_nontemporal_load(&in4[(size_t)r3 * d4 + tid]);
            a4 += __builtin_nontemporal_load(&in4[(size_t)r4 * d4 + tid]);
            a5 += __builtin_nontemporal_load(&in4[(size_t)r5 * d4 + tid]);
            a6 += __builtin_nontemporal_load(&in4[(size_t)r6 * d4 + tid]);
            a7 += __builtin_nontemporal_load(&in4[(size_t)r7 * d4 + tid]);
        }
        for (; j < mm; ++j)
            a0 += __builtin_nontemporal_load(&in4[(size_t)rows[j] * d4 + tid]);
    }
    floatx4 s = ((a0 + a1) + (a2 + a3)) + ((a4 + a5) + (a6 + a7));
    part4[(size_t)b * d4 + tid] = s;           // partial sum for this half
}

// One block per class: combine halves, divide by count, or fall back to weight.
__global__ void finalize_kernel(const floatx4* __restrict__ part4,
                                const floatx4* __restrict__ w4,
                                const int* __restrict__ counts,
                                floatx4* __restrict__ out4, int d4) {
    int c = blockIdx.x;
    int tid = threadIdx.x;
    int cnt = counts[c];
    size_t o = (size_t)c * d4 + tid;
    floatx4 r;
    if (cnt > 0) {
        floatx4 s = part4[(size_t)(c << 1) * d4 + tid]
                  + part4[(size_t)((c << 1) | 1) * d4 + tid];
        r = s * (1.0f / (float)cnt);
    } else {
        r = w4[o];
    }
    out4[o] = r;
}

extern "C" void kernel_launch(void* const* d_in, const int* in_sizes, int n_in,
                              void* d_out, int out_size, void* d_ws, size_t ws_size,
                              hipStream_t stream) {
    const float* inputs = (const float*)d_in[0];
    const int* targets  = (const int*)d_in[1];
    const float* weight = (const float*)d_in[3];

    const int N = in_sizes[1];                 // 65536
    const int D = in_sizes[0] / N;             // 1024
    const int C = in_sizes[3] / D;             // 1000
    const int D4 = D / 4;                      // 256

    int* counts  = (int*)d_ws;
    int* cursors = counts + C;
    int* offsets = cursors + C;
    int* binned  = offsets + C;
    float* part  = (float*)(binned + N);

    // 1. zero counts + cursors (ws is re-poisoned to 0xAA before every call)
    zero_kernel<<<(2 * C + 255) / 256, 256, 0, stream>>>(counts, 2 * C);

    // 2. histogram of targets
    count_kernel<<<(N + 255) / 256, 256, 0, stream>>>(targets, counts, N);

    // 3. exclusive prefix sum -> bin offsets
    scan_kernel<<<1, 1024, 0, stream>>>(counts, offsets, C);

    // 4. scatter row ids into bins
    scatter_kernel<<<(N + 255) / 256, 256, 0, stream>>>(targets, offsets, cursors, binned, N);

    // 5. per-(class,half) gather-reduce -> partials
    gather_kernel<<<2 * C, D4, 0, stream>>>(
        (const floatx4*)inputs, counts, offsets, binned, (floatx4*)part, D4);

    // 6. combine halves + mean / weight fallback
    finalize_kernel<<<C, D4, 0, stream>>>(
        (const floatx4*)part, (const floatx4*)weight, counts, (floatx4*)d_out, D4);
}